// Round 7
// baseline (319.774 us; speedup 1.0000x reference)
//
#include <hip/hip_runtime.h>
#include <float.h>

#define B 4
#define D 256
#define HH 112
#define WW 112
#define WS 7
#define NW 256
#define LL 49
#define LP 56      // padded l-dim in GLOBAL window tensors (u16)
#define TOPK 8
#define NH 8
#define DH 32
#define STK 60     // k_mid kvw LDS row stride (u16)
#define STX 60     // k_xform LDS row stride (f32): 240 B, 16B-aligned, bank-uniform

typedef unsigned short u16;
typedef unsigned int u32;

__device__ __forceinline__ float elu1(float x) {
    return x > 0.f ? x + 1.f : __expf(x);
}
__device__ __forceinline__ float bf2f(u16 u) {
    return __uint_as_float(((u32)u) << 16);
}
__device__ __forceinline__ u16 f2bf(float x) {
    u32 u = __float_as_uint(x);
    u32 r = (u + 0x7FFFu + ((u >> 16) & 1u)) >> 16;
    return (u16)r;
}
__device__ __forceinline__ u32 pack_bf16(float lo, float hi) {
    return ((u32)f2bf(hi) << 16) | f2bf(lo);
}
__device__ __forceinline__ float bflo(u32 w) { return __uint_as_float(w << 16); }
__device__ __forceinline__ float bfhi(u32 w) { return __uint_as_float(w & 0xffff0000u); }

// ---------------------------------------------------------------------------
// K0: windowize one tensor -> bf16 [b][win][c][LP] (+elu for q,k; l>=49 -> 0)
// + fp32 window means. Block = (ti, b, wi, cg4).
// Phase A: scalar coalesced reads, STRIDE-1 LDS scatter (conflict-free).
// Phase B: b128 row reads, strictly sequential fp32 accumulation (bit-
//          identical to the R6-passed scalar order).
// Phase C: b128 reads -> elu -> bf16 pack -> contiguous global writes.
// ---------------------------------------------------------------------------
__global__ __launch_bounds__(256) void k_xform(
        const float* __restrict__ q, const float* __restrict__ k,
        const float* __restrict__ v,
        u16* __restrict__ qwin, u16* __restrict__ kwin, u16* __restrict__ vwin,
        float* __restrict__ qm, float* __restrict__ kmf,
        float* __restrict__ vm, float* __restrict__ kmT) {
    __shared__ float st[4 * 16 * STX];   // [c][wj] rows, stride 60 = 15360 B
    int blk = blockIdx.x;
    int cg = blk & 63, wi = (blk >> 6) & 15, b = (blk >> 10) & 3, ti = blk >> 12;
    int c0 = cg * 4;
    int t = threadIdx.x;
    const float* src = ti == 0 ? q : (ti == 1 ? k : v);
    u16* dst = ti == 0 ? qwin : (ti == 1 ? kwin : vwin);

    // zero the l=49..55 pad (phase C reads l<56; pads must stay 0 in output)
    if (t < 448) {
        int row = t / 7, pl = t % 7;
        st[row * STX + 49 + pl] = 0.f;
    }
    // phase A: coalesced scalar reads; stride-1 scatter to window-major LDS
    {
        const float* base0 = src + (size_t)(b * D + c0) * (HH * WW) + wi * 784;
        for (int p = t; p < 3136; p += 256) {
            int c = p / 784;
            int i = p - c * 784;
            int r = i / 112;
            int x = i - r * 112;
            int wj = (x * 9363) >> 16;          // x/7, exact for x<112
            float val = base0[p + c * 11760];   // 11760 = HH*WW - 784
            // row (c*16+wj), offset r*7 + (x - wj*7)
            st[c * (16 * STX) + wj * (STX - 7) + r * 7 + x] = val;
        }
    }
    __syncthreads();
    // phase B: fp32 means, b128 loads + sequential adds (same fp32 result
    // as the scalar sequential loop -- add order unchanged)
    if (t < 64) {
        const float* row = st + t * STX;        // t = c*16+wj
        float s = 0.f;
        for (int j = 0; j < 12; ++j) {
            float4 f = *(const float4*)(row + j * 4);
            s += f.x; s += f.y; s += f.z; s += f.w;
        }
        s += row[48];
        float mean = s * (1.f / 49.f);
        int c = t >> 4, wj = t & 15;
        int C = c0 + c;
        int win = wi * 16 + wj;
        if (ti == 0) qm[(size_t)(b * NW + win) * D + C] = mean;
        else if (ti == 1) {
            kmf[(size_t)(b * NW + win) * D + C] = elu1(mean);
            kmT[(size_t)(b * D + C) * NW + win] = mean;
        } else vm[(size_t)(b * NW + win) * D + C] = mean;
    }
    __syncthreads();
    // phase C: vector LDS reads -> elu (q,k) -> packed bf16 -> contiguous
    for (int p = t; p < 448; p += 256) {
        int wj = p / 28;
        int rem = p - wj * 28;
        int c = rem / 7, j = rem - c * 7;
        const float* row = st + (c * 16 + wj) * STX + j * 8;
        float4 f0 = *(const float4*)row;
        float4 f1 = *(const float4*)(row + 4);
        if (ti < 2) {
            f0.x = elu1(f0.x); f0.y = elu1(f0.y);
            f0.z = elu1(f0.z); f0.w = elu1(f0.w);
            f1.x = elu1(f1.x); f1.y = elu1(f1.y);
            f1.z = elu1(f1.z); f1.w = elu1(f1.w);
            if (j == 6) { // l=49..55 pad: elu1(0)=1, must stay 0
                f0.y = 0.f; f0.z = 0.f; f0.w = 0.f;
                f1.x = 0.f; f1.y = 0.f; f1.z = 0.f; f1.w = 0.f;
            }
        }
        uint4 o = make_uint4(pack_bf16(f0.x, f0.y), pack_bf16(f0.z, f0.w),
                             pack_bf16(f1.x, f1.y), pack_bf16(f1.z, f1.w));
        int win = wi * 16 + wj;
        u16* gp = dst + ((size_t)(b * NW + win) * D + c0 + c) * LP + j * 8;
        *(uint4*)gp = o;
    }
}

// ---------------------------------------------------------------------------
// K_mid: fused. Blocks [0,1024): top-8 selection. [1024,3072): per-(b,win,
// half) KVw(bf16)+Ksw. [3072,3080): coarse KV over mean tokens.
// ---------------------------------------------------------------------------
__global__ __launch_bounds__(256) void k_mid(
        const u16* __restrict__ kwin, const u16* __restrict__ vwin,
        const float* __restrict__ qm, const float* __restrict__ kmT,
        const float* __restrict__ kmf, const float* __restrict__ vm,
        int* __restrict__ idx,
        u16* __restrict__ KVw, float* __restrict__ Ksw,
        float* __restrict__ KVc, float* __restrict__ Ksc) {
    __shared__ u16 kf[128 * STK];   // 15360 B
    __shared__ u16 vf[128 * STK];
    int blk = blockIdx.x;
    int t = threadIdx.x;
    if (blk < B * NW) {
        // ---- top-k ----
        float* qrow = (float*)kf;              // 256 floats
        float* cval = qrow + 256;              // 4
        int* cidx = (int*)(qrow + 260);        // 4
        int* winner = cidx + 4;
        int b = blk >> 8;
        int qw = blk & 255;
        qrow[t] = qm[(size_t)(b * NW + qw) * D + t];
        __syncthreads();
        const float* kb = kmT + (size_t)b * D * NW + t;
        float a0 = 0.f, a1 = 0.f, a2 = 0.f, a3 = 0.f;
        for (int d = 0; d < D; d += 4) {
            a0 += qrow[d]     * kb[(size_t)d * NW];
            a1 += qrow[d + 1] * kb[(size_t)(d + 1) * NW];
            a2 += qrow[d + 2] * kb[(size_t)(d + 2) * NW];
            a3 += qrow[d + 3] * kb[(size_t)(d + 3) * NW];
        }
        float val = (a0 + a1) + (a2 + a3);
        for (int sel = 0; sel < TOPK; ++sel) {
            float vv = val; int ii = t;
            for (int off = 32; off > 0; off >>= 1) {
                float ov = __shfl_xor(vv, off);
                int oi = __shfl_xor(ii, off);
                if (ov > vv || (ov == vv && oi < ii)) { vv = ov; ii = oi; }
            }
            if ((t & 63) == 0) { cval[t >> 6] = vv; cidx[t >> 6] = ii; }
            __syncthreads();
            if (t == 0) {
                float bv = cval[0]; int bi = cidx[0];
                for (int w = 1; w < 4; ++w)
                    if (cval[w] > bv || (cval[w] == bv && cidx[w] < bi)) {
                        bv = cval[w]; bi = cidx[w];
                    }
                idx[(size_t)(b * NW + qw) * TOPK + sel] = bi;
                *winner = bi;
            }
            __syncthreads();
            if (t == *winner) val = -FLT_MAX;
        }
        return;
    }
    if (blk >= B * NW + B * NW * 2) {
        // ---- coarse KV (fp32 path) ----
        int blkc = blk - (B * NW + B * NW * 2);
        int b = blkc >> 1, half = blkc & 1;
        int h2 = t >> 6, q64 = t & 63, ddq = q64 >> 3, dvq = q64 & 7;
        int ca = half * 128 + h2 * 32 + ddq * 4;
        int cb = half * 128 + h2 * 32 + dvq * 4;
        const float* kb = kmf + (size_t)b * NW * D;
        const float* vb = vm + (size_t)b * NW * D;
        float acc[4][4] = {};
        float ks[4] = {};
        for (int n = 0; n < NW; ++n) {
            float4 a  = *(const float4*)&kb[n * D + ca];
            float4 bv = *(const float4*)&vb[n * D + cb];
            float av[4] = {a.x, a.y, a.z, a.w};
            float bw[4] = {bv.x, bv.y, bv.z, bv.w};
            ks[0] += av[0]; ks[1] += av[1]; ks[2] += av[2]; ks[3] += av[3];
            for (int i = 0; i < 4; ++i)
                for (int j = 0; j < 4; ++j)
                    acc[i][j] += av[i] * bw[j];
        }
        int h = half * 4 + h2;
        size_t obase = (size_t)(b * NH + h) * (DH * DH);
        for (int i = 0; i < 4; ++i) {
            float4 o = {acc[i][0], acc[i][1], acc[i][2], acc[i][3]};
            *(float4*)&KVc[obase + (size_t)(ddq * 4 + i) * DH + dvq * 4] = o;
        }
        if (dvq == 0) {
            float4 o = {ks[0], ks[1], ks[2], ks[3]};
            *(float4*)&Ksc[(size_t)(b * NH + h) * DH + ddq * 4] = o;
        }
        return;
    }
    // ---- per-window KV ----
    int blkw = blk - B * NW;
    int b = blkw >> 9;
    int win = (blkw >> 1) & 255;
    int half = blkw & 1;
    const u16* kg = kwin + ((size_t)(b * NW + win) * D + half * 128) * LP;
    const u16* vg = vwin + ((size_t)(b * NW + win) * D + half * 128) * LP;
    for (int p = t; p < 896; p += 256) {
        int c = p / 7, j = p % 7;
        uint4 kq = *(const uint4*)(kg + c * LP + j * 8);
        uint4 vq = *(const uint4*)(vg + c * LP + j * 8);
        *(uint2*)&kf[c * STK + j * 8]     = make_uint2(kq.x, kq.y);
        *(uint2*)&kf[c * STK + j * 8 + 4] = make_uint2(kq.z, kq.w);
        *(uint2*)&vf[c * STK + j * 8]     = make_uint2(vq.x, vq.y);
        *(uint2*)&vf[c * STK + j * 8 + 4] = make_uint2(vq.z, vq.w);
    }
    __syncthreads();
    int h2 = t >> 6, q64 = t & 63, ddq = q64 >> 3, dvq = q64 & 7;
    const u16* ka = kf + (h2 * 32 + ddq * 4) * STK;
    const u16* vb = vf + (h2 * 32 + dvq * 4) * STK;
    float acc[4][4] = {};
    float ks[4] = {};
    for (int l4 = 0; l4 < 14; ++l4) {
        float a[4][4], w[4][4];
        for (int i = 0; i < 4; ++i) {
            uint2 kr = *(const uint2*)(ka + i * STK + l4 * 4);
            a[i][0] = bflo(kr.x); a[i][1] = bfhi(kr.x);
            a[i][2] = bflo(kr.y); a[i][3] = bfhi(kr.y);
            uint2 vr = *(const uint2*)(vb + i * STK + l4 * 4);
            w[i][0] = bflo(vr.x); w[i][1] = bfhi(vr.x);
            w[i][2] = bflo(vr.y); w[i][3] = bfhi(vr.y);
        }
        for (int i = 0; i < 4; ++i) {
            ks[i] += (a[i][0] + a[i][1]) + (a[i][2] + a[i][3]);
            for (int j = 0; j < 4; ++j)
                for (int s = 0; s < 4; ++s)
                    acc[i][j] += a[i][s] * w[j][s];
        }
    }
    int h = half * 4 + h2;
    u16* ob = KVw + (size_t)((b * NW + win) * NH + h) * (DH * DH);
    for (int i = 0; i < 4; ++i) {
        u32 p0 = pack_bf16(acc[i][0], acc[i][1]);
        u32 p1 = pack_bf16(acc[i][2], acc[i][3]);
        *(uint2*)(ob + (ddq * 4 + i) * DH + dvq * 4) = make_uint2(p0, p1);
    }
    if (dvq == 0) {
        float4 o = {ks[0], ks[1], ks[2], ks[3]};
        *(float4*)&Ksw[(size_t)((b * NW + win) * NH + h) * DH + ddq * 4] = o;
    }
}

// ---------------------------------------------------------------------------
// K4: gather-sum KV (bf16 KVw + fp32 coarse), apply Qf, write msg rows
// directly from registers (channel-major, aliases qwin). XCD swizzle.
// ---------------------------------------------------------------------------
__global__ __launch_bounds__(256) void k_final(
        const u16* qwin, const int* __restrict__ idx,
        const u16* __restrict__ KVw, const float* __restrict__ Ksw,
        const float* __restrict__ KVc, const float* __restrict__ Ksc,
        u16* msg) {
    __shared__ float kv[4 * DH * DH];   // 16 KB
    __shared__ float ksl[4 * DH];
    __shared__ u16 qf[128 * LP];        // 14336 B
    __shared__ int idxl[TOPK];
    int blk = blockIdx.x;
    int lin = ((blk & 7) << 8) | (blk >> 3);   // XCD swizzle
    int half = lin & 1;
    int qw = (lin >> 1) & 255;
    int b = lin >> 9;
    int t = threadIdx.x;
    if (t < TOPK) idxl[t] = idx[(size_t)(b * NW + qw) * TOPK + t];
    const u16* qg = qwin + ((size_t)(b * NW + qw) * D + half * 128) * LP;
    for (int p = t; p < 896; p += 256)
        *(uint4*)&qf[p * 8] = *(const uint4*)(qg + p * 8);
    __syncthreads();
    {
        int h2 = t >> 6;
        int dd = (t & 63) >> 1;
        int dvh = t & 1;
        int h = half * 4 + h2;
        float kvacc[16] = {};
        float ksacc = 0.f;
        for (int s = 0; s < TOPK; ++s) {
            int srcw = idxl[s];
            const u16* rp = KVw + (size_t)((b * NW + srcw) * NH + h) * (DH * DH)
                            + dd * DH + dvh * 16;
            uint4 r0 = *(const uint4*)rp;
            uint4 r1 = *(const uint4*)(rp + 8);
            u32 wsv[4] = {r0.x, r0.y, r0.z, r0.w};
            for (int h4 = 0; h4 < 4; ++h4) {
                kvacc[h4 * 2]     += bflo(wsv[h4]);
                kvacc[h4 * 2 + 1] += bfhi(wsv[h4]);
            }
            u32 wsv1[4] = {r1.x, r1.y, r1.z, r1.w};
            for (int h4 = 0; h4 < 4; ++h4) {
                kvacc[8 + h4 * 2]     += bflo(wsv1[h4]);
                kvacc[8 + h4 * 2 + 1] += bfhi(wsv1[h4]);
            }
            ksacc += Ksw[(size_t)((b * NW + srcw) * NH + h) * DH + dd];
        }
        {
            const float* rowp = KVc + (size_t)(b * NH + h) * (DH * DH)
                                + dd * DH + dvh * 16;
            for (int j4 = 0; j4 < 4; ++j4) {
                float4 r4 = *(const float4*)&rowp[j4 * 4];
                kvacc[j4 * 4 + 0] += r4.x; kvacc[j4 * 4 + 1] += r4.y;
                kvacc[j4 * 4 + 2] += r4.z; kvacc[j4 * 4 + 3] += r4.w;
            }
            ksacc += Ksc[(size_t)(b * NH + h) * DH + dd];
        }
        for (int j = 0; j < 16; ++j)
            kv[h2 * (DH * DH) + dd * DH + dvh * 16 + j] = kvacc[j];
        if (dvh == 0) ksl[h2 * DH + dd] = ksacc;
    }
    __syncthreads();
    {
        int lset = t >> 7;                // l0 = 0 or 28
        int h2 = (t >> 5) & 3;
        int dv = t & 31;
        int l0 = lset * 28;
        float m[28] = {}, z[28] = {};
        for (int dd = 0; dd < DH; ++dd) {
            float kc = kv[h2 * (DH * DH) + dd * DH + dv];
            float ko = ksl[h2 * DH + dd];
            const u16* qr = qf + (h2 * 32 + dd) * LP + l0;
#pragma unroll
            for (int u = 0; u < 7; ++u) {
                uint2 qq = *(const uint2*)(qr + u * 4);
                float q0 = bflo(qq.x), q1 = bfhi(qq.x);
                float q2 = bflo(qq.y), q3 = bfhi(qq.y);
                m[u * 4 + 0] += q0 * kc; z[u * 4 + 0] += q0 * ko;
                m[u * 4 + 1] += q1 * kc; z[u * 4 + 1] += q1 * ko;
                m[u * 4 + 2] += q2 * kc; z[u * 4 + 2] += q2 * ko;
                m[u * 4 + 3] += q3 * kc; z[u * 4 + 3] += q3 * ko;
            }
        }
        u16 r[28];
#pragma unroll
        for (int l = 0; l < 28; ++l)
            r[l] = f2bf(m[l] / (z[l] + 1e-6f));
        int C = half * 128 + h2 * 32 + dv;
        u16* mg = msg + ((size_t)(b * NW + qw) * D + C) * LP + l0;
        if (lset == 0) {
            for (int u = 0; u < 7; ++u)
                *(uint2*)(mg + u * 4) = make_uint2(
                    ((u32)r[u * 4 + 1] << 16) | r[u * 4],
                    ((u32)r[u * 4 + 3] << 16) | r[u * 4 + 2]);
        } else {
            for (int u = 0; u < 5; ++u)
                *(uint2*)(mg + u * 4) = make_uint2(
                    ((u32)r[u * 4 + 1] << 16) | r[u * 4],
                    ((u32)r[u * 4 + 3] << 16) | r[u * 4 + 2]);
            mg[20] = r[20];
        }
    }
}

// ---------------------------------------------------------------------------
// K5: channel-major msg -> image layout, full-line coalesced writes.
// ---------------------------------------------------------------------------
__global__ __launch_bounds__(256) void k_out(
        const u16* __restrict__ msg, float* __restrict__ out) {
    __shared__ u16 ms[16 * 16 * LP];   // 28672 B
    int blk = blockIdx.x;
    int cg = blk & 15, wi = (blk >> 4) & 15, b = blk >> 8;
    int c0 = cg * 16;
    int t = threadIdx.x;
    for (int p = t; p < 1792; p += 256) {
        int wjl = p / 112;
        int rem = p - wjl * 112;
        int c = rem / 7, j = rem % 7;
        const u16* gp = msg +
            ((size_t)(b * NW + wi * 16 + wjl) * D + c0 + c) * LP + j * 8;
        *(uint4*)&ms[(wjl * 16 + c) * LP + j * 8] = *(const uint4*)gp;
    }
    __syncthreads();
    for (int p = t; p < 3136; p += 256) {
        int c = p / 196;
        int f4 = (p - c * 196) * 4;
        int r = f4 / 112, col = f4 - r * 112;
        float4 o;
        float* op = (float*)&o;
        for (int j = 0; j < 4; ++j) {
            int xg = col + j;
            int wj = xg / 7, x = xg - wj * 7;
            int l = r * 7 + x;
            op[j] = bf2f(ms[(wj * 16 + c) * LP + l]);
        }
        float* gp = out + (size_t)(b * D + c0 + c) * (HH * WW)
                    + (wi * WS + r) * WW + col;
        *(float4*)gp = o;
    }
}

// ---------------------------------------------------------------------------
extern "C" void kernel_launch(void* const* d_in, const int* in_sizes, int n_in,
                              void* d_out, int out_size, void* d_ws, size_t ws_size,
                              hipStream_t stream) {
    const float* q = (const float*)d_in[0];
    const float* k = (const float*)d_in[1];
    const float* v = (const float*)d_in[2];
    float* out = (float*)d_out;
    char* base = (char*)d_ws;

    const size_t MB = 1 << 20;
    float* qm  = (float*)(base);                       // 1 MiB
    float* kmf = (float*)(base + 1 * MB);              // 1 MiB
    float* vm  = (float*)(base + 2 * MB);              // 1 MiB
    float* kmT = (float*)(base + 3 * MB);              // 1 MiB
    int*   idx = (int*)  (base + 4 * MB);              // 32 KiB
    float* Ksw = (float*)(base + 4 * MB + (1 << 15));  // 1 MiB
    float* KVc = (float*)(base + 5 * MB + (1 << 15));  // 128 KiB
    float* Ksc = (float*)(base + 5 * MB + (1 << 15) + (1 << 17)); // 4 KiB
    u16* KVw  = (u16*)(base + 6 * MB);                 // 16 MiB (bf16)
    u16* kwin = (u16*)(base + 24 * MB);                // 28 MiB
    u16* vwin = (u16*)(base + 52 * MB);                // 28 MiB
    u16* qwin = (u16*)(base + 80 * MB);                // 28 MiB (msg alias)

    k_xform<<<dim3(3 * B * 16 * 64), dim3(256), 0, stream>>>(
        q, k, v, qwin, kwin, vwin, qm, kmf, vm, kmT);
    k_mid  <<<dim3(B * NW + B * NW * 2 + B * 2), dim3(256), 0, stream>>>(
        kwin, vwin, qm, kmT, kmf, vm, idx, KVw, Ksw, KVc, Ksc);
    k_final<<<dim3(B * NW * 2), dim3(256), 0, stream>>>(
        qwin, idx, KVw, Ksw, KVc, Ksc, qwin /* msg aliases qwin per-block */);
    k_out  <<<dim3(B * 16 * 16), dim3(256), 0, stream>>>(qwin, out);
}